// Round 3
// baseline (488.940 us; speedup 1.0000x reference)
//
#include <hip/hip_runtime.h>
#include <stdint.h>
#include <stddef.h>

// EdgeLearning: out[e] = W2 @ leaky(W1 @ [x[ei0[e]], x[ei1[e]], ea[e]] + b1) + b2
// bf16 MFMA (16x16x32), fp32 accumulate. Layouts per verified gfx950 mappings:
//   A frag: A[m=lane&15][k=quad*8+j]   B frag: B[n=lane&15][k=quad*8+j]
//   C/D:    col=lane&15, row=quad*4+reg
// Round 3: REVERT to the round-0 shape (256 thr, 128 edges/block, grid 1250,
// scalar round-0 stores) whose traffic profile was clean (FETCH 220 / WRITE
// 200 MB); the 512-thr shape inflated traffic +70% regardless of store
// pattern. On top of round 0, two latency-targeting changes only:
//  (1) x pre-converted to bf16 in workspace (half gather bytes, no cvt burst
//      on the critical path),
//  (2) two-stage software pipeline per wave: while computing tile t, the ei
//      indices for t+2*grid and the gathers/ea for t+1*grid are already in
//      flight (T14). Compute (~112 MFMA) hides the ~600-900 cyc gather chain.

typedef short short8 __attribute__((ext_vector_type(8)));
typedef float f32x4 __attribute__((ext_vector_type(4)));

__device__ __forceinline__ short f2bf(float f) {
  union { float f; unsigned u; } v; v.f = f;
  unsigned r = (v.u + 0x7fffu + ((v.u >> 16) & 1u)) >> 16;  // RNE
  return (short)r;
}

__device__ __forceinline__ short8 cvt8(const float* __restrict__ p) {
  f32x4 a = *(const f32x4*)p;
  f32x4 b = *(const f32x4*)(p + 4);
  short8 r;
  r[0] = f2bf(a[0]); r[1] = f2bf(a[1]); r[2] = f2bf(a[2]); r[3] = f2bf(a[3]);
  r[4] = f2bf(b[0]); r[5] = f2bf(b[1]); r[6] = f2bf(b[2]); r[7] = f2bf(b[3]);
  return r;
}

// Pre-convert x (fp32) -> bf16 bits in workspace. Same RNE as cvt8, so the
// MFMA inputs are bit-identical to the fp32-gather path.
__global__ __launch_bounds__(256)
void cvt_x_kernel(const float* __restrict__ x, short* __restrict__ xb, int n8) {
  int i = blockIdx.x * blockDim.x + threadIdx.x;
  if (i < n8) *(short8*)(xb + (size_t)i * 8) = cvt8(x + (size_t)i * 8);
}

template <bool XB>
__global__ __launch_bounds__(256, 2)
void edge_mlp(const float* __restrict__ x, const short* __restrict__ xb,
              const int* __restrict__ ei, const float* __restrict__ ea,
              const float* __restrict__ W1, const float* __restrict__ b1,
              const float* __restrict__ W2, const float* __restrict__ b2,
              float* __restrict__ out, int E, int ntiles)
{
  __shared__ short sW1[128 * 168];   // bf16 bits, padded rows (43008 B)
  __shared__ short sH[4][32 * 40];   // per-wave h chunk -> total 53248 B

  const int tid  = threadIdx.x;
  const int lane = tid & 63;
  const int wave = tid >> 6;
  const int m    = lane & 15;
  const int quad = lane >> 4;

  // Stage W1 -> LDS as bf16 (once per block; amortized over grid-stride tiles)
  for (int i = tid; i < 128 * 160; i += 256) {
    int n = i / 160;
    int k = i - n * 160;
    sW1[n * 168 + k] = f2bf(W1[i]);
  }

  // W2 fragments in registers: B2[k][o], o = ot*16+m, k = c*32 + quad*8 + j
  short8 w2f[4][4];
#pragma unroll
  for (int ot = 0; ot < 4; ++ot)
#pragma unroll
    for (int c = 0; c < 4; ++c)
      w2f[ot][c] = cvt8(W2 + (size_t)(ot * 16 + m) * 128 + c * 32 + quad * 8);

  float b1v[8], b2v[4];
#pragma unroll
  for (int nt = 0; nt < 8; ++nt) b1v[nt] = b1[nt * 16 + m];
#pragma unroll
  for (int ot = 0; ot < 4; ++ot) b2v[ot] = b2[ot * 16 + m];

  __syncthreads();

  short* sHw = sH[wave];

  // Round-0 compute core (exact), consuming prebuilt a1 fragments.
  auto compute_store = [&](int tt, const short8 (&a1)[2][5]) {
    const int ebase = tt * 128 + wave * 32;

    f32x4 acc2[2][4];
#pragma unroll
    for (int mt = 0; mt < 2; ++mt)
#pragma unroll
      for (int ot = 0; ot < 4; ++ot) {
        f32x4 z = { b2v[ot], b2v[ot], b2v[ot], b2v[ot] };
        acc2[mt][ot] = z;
      }

#pragma unroll
    for (int c = 0; c < 4; ++c) {
#pragma unroll
      for (int sub = 0; sub < 2; ++sub) {
        const int nt = c * 2 + sub;
        f32x4 h0 = { b1v[nt], b1v[nt], b1v[nt], b1v[nt] };
        f32x4 h1 = h0;
#pragma unroll
        for (int kt = 0; kt < 5; ++kt) {
          short8 bf = *(const short8*)&sW1[(nt * 16 + m) * 168 + kt * 32 + quad * 8];
          h0 = __builtin_amdgcn_mfma_f32_16x16x32_bf16(a1[0][kt], bf, h0, 0, 0, 0);
          h1 = __builtin_amdgcn_mfma_f32_16x16x32_bf16(a1[1][kt], bf, h1, 0, 0, 0);
        }
#pragma unroll
        for (int r = 0; r < 4; ++r) {
          float v0 = h0[r]; v0 = (v0 >= 0.0f) ? v0 : 0.01f * v0;
          float v1 = h1[r]; v1 = (v1 >= 0.0f) ? v1 : 0.01f * v1;
          sHw[(quad * 4 + r) * 40 + sub * 16 + m]      = f2bf(v0);
          sHw[(16 + quad * 4 + r) * 40 + sub * 16 + m] = f2bf(v1);
        }
      }
#pragma unroll
      for (int mt = 0; mt < 2; ++mt) {
        short8 a2 = *(const short8*)&sHw[(mt * 16 + m) * 40 + quad * 8];
#pragma unroll
        for (int ot = 0; ot < 4; ++ot)
          acc2[mt][ot] = __builtin_amdgcn_mfma_f32_16x16x32_bf16(a2, w2f[ot][c], acc2[mt][ot], 0, 0, 0);
      }
    }

#pragma unroll
    for (int mt = 0; mt < 2; ++mt)
#pragma unroll
      for (int ot = 0; ot < 4; ++ot)
#pragma unroll
        for (int r = 0; r < 4; ++r) {
          int er = ebase + mt * 16 + quad * 4 + r;
          if (er < E) out[(size_t)er * 64 + ot * 16 + m] = acc2[mt][ot][r];
        }
  };

  if constexpr (!XB) {
    // Fallback (no workspace): round-0 behavior, unpipelined fp32 gather.
    for (int t = blockIdx.x; t < ntiles; t += gridDim.x) {
      const int ebase = t * 128 + wave * 32;
      short8 a1[2][5];
#pragma unroll
      for (int mt = 0; mt < 2; ++mt) {
        int e = ebase + mt * 16 + m;
        e = (e < E) ? e : (E - 1);
        const int i0 = ei[e];
        const int i1 = ei[E + e];
        const float* r0 = x + (size_t)i0 * 64 + quad * 8;
        const float* r1 = x + (size_t)i1 * 64 + quad * 8;
        a1[mt][0] = cvt8(r0);
        a1[mt][1] = cvt8(r0 + 32);
        a1[mt][2] = cvt8(r1);
        a1[mt][3] = cvt8(r1 + 32);
        a1[mt][4] = cvt8(ea + (size_t)e * 32 + quad * 8);
      }
      compute_store(t, a1);
    }
    return;
  } else {
    // Two-stage pipelined path: idx 2 tiles ahead, gathers/ea 1 tile ahead.
    const int g1 = gridDim.x;
    const int tlast = ntiles - 1;
    auto clampt = [&](int tt) { return tt < ntiles ? tt : tlast; };

    auto load_idx = [&](int tt, int (&idx)[2][2]) {
      const int eb = tt * 128 + wave * 32;
#pragma unroll
      for (int mt = 0; mt < 2; ++mt) {
        int e = eb + mt * 16 + m;
        e = (e < E) ? e : (E - 1);
        idx[mt][0] = ei[e];
        idx[mt][1] = ei[E + e];
      }
    };
    auto load_gather = [&](int tt, const int (&idx)[2][2],
                           short8 (&g)[2][4], f32x4 (&ef)[2][2]) {
      const int eb = tt * 128 + wave * 32;
#pragma unroll
      for (int mt = 0; mt < 2; ++mt) {
        int e = eb + mt * 16 + m;
        e = (e < E) ? e : (E - 1);
        const short* r0 = xb + (size_t)idx[mt][0] * 64 + quad * 8;
        const short* r1 = xb + (size_t)idx[mt][1] * 64 + quad * 8;
        g[mt][0] = *(const short8*)r0;
        g[mt][1] = *(const short8*)(r0 + 32);
        g[mt][2] = *(const short8*)r1;
        g[mt][3] = *(const short8*)(r1 + 32);
        const float* pe = ea + (size_t)e * 32 + quad * 8;
        ef[mt][0] = *(const f32x4*)pe;
        ef[mt][1] = *(const f32x4*)(pe + 4);
      }
    };
    auto build_a1 = [&](const short8 (&g)[2][4], const f32x4 (&ef)[2][2],
                        short8 (&a1)[2][5]) {
#pragma unroll
      for (int mt = 0; mt < 2; ++mt) {
        a1[mt][0] = g[mt][0];
        a1[mt][1] = g[mt][1];
        a1[mt][2] = g[mt][2];
        a1[mt][3] = g[mt][3];
        short8 r;
        r[0] = f2bf(ef[mt][0][0]); r[1] = f2bf(ef[mt][0][1]);
        r[2] = f2bf(ef[mt][0][2]); r[3] = f2bf(ef[mt][0][3]);
        r[4] = f2bf(ef[mt][1][0]); r[5] = f2bf(ef[mt][1][1]);
        r[6] = f2bf(ef[mt][1][2]); r[7] = f2bf(ef[mt][1][3]);
        a1[mt][4] = r;
      }
    };

    int t = blockIdx.x;
    if (t >= ntiles) return;

    int   idxA[2][2], idxB[2][2];
    short8 gA[2][4], gB[2][4];
    f32x4  eaA[2][2], eaB[2][2];

    // Prologue: gather tile t; preload indices for t+g1.
    load_idx(t, idxA);
    load_gather(t, idxA, gA, eaA);
    load_idx(clampt(t + g1), idxA);

    bool phase = true;  // true: A holds current tile, idxA holds t+g1 indices
    for (; t < ntiles; t += g1) {
      const int tg = clampt(t + g1);       // gather target
      const int ti = clampt(t + 2 * g1);   // idx target
      short8 a1[2][5];
      if (phase) {
        load_idx(ti, idxB);                // issue earliest (longest chain)
        load_gather(tg, idxA, gB, eaB);    // in flight under compute(t)
        build_a1(gA, eaA, a1);
        compute_store(t, a1);
      } else {
        load_idx(ti, idxA);
        load_gather(tg, idxB, gA, eaA);
        build_a1(gB, eaB, a1);
        compute_store(t, a1);
      }
      phase = !phase;
    }
  }
}

extern "C" void kernel_launch(void* const* d_in, const int* in_sizes, int n_in,
                              void* d_out, int out_size, void* d_ws, size_t ws_size,
                              hipStream_t stream) {
  const float* x  = (const float*)d_in[0];
  const int*   ei = (const int*)d_in[1];
  const float* ea = (const float*)d_in[2];
  const float* W1 = (const float*)d_in[3];
  const float* b1 = (const float*)d_in[4];
  const float* W2 = (const float*)d_in[5];
  const float* b2 = (const float*)d_in[6];
  float* out = (float*)d_out;

  const int E  = in_sizes[1] / 2;           // edge_index is [2, E]
  const int nx = in_sizes[0];               // N_NODES * DIM_NODE floats
  const int ntiles = (E + 127) / 128;       // 128 edges per block (32 per wave)
  int grid = ntiles < 1250 ? ntiles : 1250; // round-0 persistent shape

  short* xb = (short*)d_ws;
  const bool usebf = (d_ws != nullptr) && (ws_size >= (size_t)nx * sizeof(short))
                     && ((nx & 7) == 0);
  if (usebf) {
    const int n8 = nx / 8;
    const int cg = (n8 + 255) / 256;
    cvt_x_kernel<<<cg, 256, 0, stream>>>(x, xb, n8);
    edge_mlp<true><<<grid, 256, 0, stream>>>(x, xb, ei, ea, W1, b1, W2, b2, out, E, ntiles);
  } else {
    edge_mlp<false><<<grid, 256, 0, stream>>>(x, nullptr, ei, ea, W1, b1, W2, b2, out, E, ntiles);
  }
}

// Round 4
// 384.065 us; speedup vs baseline: 1.2731x; 1.2731x over previous
//
#include <hip/hip_runtime.h>
#include <stdint.h>
#include <stddef.h>

// EdgeLearning: out[e] = W2 @ leaky(W1 @ [x[ei0[e]], x[ei1[e]], ea[e]] + b1) + b2
// bf16 MFMA (16x16x32), fp32 accumulate. Layouts per verified gfx950 mappings:
//   A frag: A[m=lane&15][k=quad*8+j]   B frag: B[n=lane&15][k=quad*8+j]
//   C/D:    col=lane&15, row=quad*4+reg
// Round 4: rounds 1-3 regressions were VGPR SPILLS (symmetric FETCH+WRITE
// inflation = scratch round-trips; R1/R2 capped at 64 regs with w2f=64 regs
// alone). This round raises occupancy to 16 waves/CU the spill-free way:
//  (1) W2 fragments moved to LDS in frag-order (ds_read_b128 @ lane*16,
//      conflict-free) -> frees 64 VGPRs.
//  (2) bf16 xb gathers (half gather bytes, no cvt burst on critical path).
//  (3) 512-thr blocks, launch_bounds(512,4): LDS 79872 <= 81920 -> 2 blk/CU
//      = 16 waves/CU at VGPR cap 128; live set ~120 fits.
//  (4) NO software pipeline (that's what spilled in R3). Pure TLP.
//  (5) Store/load pattern byte-identical to round 0 (proven WRITE=200MB).

typedef short short8 __attribute__((ext_vector_type(8)));
typedef float f32x4 __attribute__((ext_vector_type(4)));

__device__ __forceinline__ short f2bf(float f) {
  union { float f; unsigned u; } v; v.f = f;
  unsigned r = (v.u + 0x7fffu + ((v.u >> 16) & 1u)) >> 16;  // RNE
  return (short)r;
}

__device__ __forceinline__ short8 cvt8(const float* __restrict__ p) {
  f32x4 a = *(const f32x4*)p;
  f32x4 b = *(const f32x4*)(p + 4);
  short8 r;
  r[0] = f2bf(a[0]); r[1] = f2bf(a[1]); r[2] = f2bf(a[2]); r[3] = f2bf(a[3]);
  r[4] = f2bf(b[0]); r[5] = f2bf(b[1]); r[6] = f2bf(b[2]); r[7] = f2bf(b[3]);
  return r;
}

// Pre-convert x (fp32) -> bf16 bits in workspace. Same RNE as cvt8, so the
// MFMA inputs are bit-identical to the fp32-gather path.
__global__ __launch_bounds__(256)
void cvt_x_kernel(const float* __restrict__ x, short* __restrict__ xb, int n8) {
  int i = blockIdx.x * blockDim.x + threadIdx.x;
  if (i < n8) *(short8*)(xb + (size_t)i * 8) = cvt8(x + (size_t)i * 8);
}

template <bool XB>
__global__ __launch_bounds__(512, 4)
void edge_mlp(const float* __restrict__ x, const short* __restrict__ xb,
              const int* __restrict__ ei, const float* __restrict__ ea,
              const float* __restrict__ W1, const float* __restrict__ b1,
              const float* __restrict__ W2, const float* __restrict__ b2,
              float* __restrict__ out, int E, int ntiles)
{
  __shared__ short  sW1[128 * 168];   // bf16 bits, padded rows (43008 B)
  __shared__ short8 sW2f[16 * 64];    // W2 frags, frag-order (16384 B)
  __shared__ short  sH[8][32 * 40];   // per-wave h chunk (20480 B) => 79872 B

  const int tid  = threadIdx.x;
  const int lane = tid & 63;
  const int wave = tid >> 6;
  const int m    = lane & 15;
  const int quad = lane >> 4;

  // Stage W1 -> LDS as bf16 (once per block; amortized over grid-stride tiles)
  for (int i = tid; i < 128 * 160; i += 512) {
    int n = i / 160;
    int k = i - n * 160;
    sW1[n * 168 + k] = f2bf(W1[i]);
  }

  // Stage W2 fragments -> LDS in frag order: frag (ot,c) for this lane is
  // B2[n=ot*16+m][k=c*32+quad*8+j]. Read back at lane*16B: conflict-free.
  if (wave == 0) {
#pragma unroll
    for (int ot = 0; ot < 4; ++ot)
#pragma unroll
      for (int c = 0; c < 4; ++c)
        sW2f[(ot * 4 + c) * 64 + lane] =
            cvt8(W2 + (size_t)(ot * 16 + m) * 128 + c * 32 + quad * 8);
  }

  float b1v[8], b2v[4];
#pragma unroll
  for (int nt = 0; nt < 8; ++nt) b1v[nt] = b1[nt * 16 + m];
#pragma unroll
  for (int ot = 0; ot < 4; ++ot) b2v[ot] = b2[ot * 16 + m];

  __syncthreads();

  short* sHw = sH[wave];

  for (int t = blockIdx.x; t < ntiles; t += gridDim.x) {
    const int ebase = t * 256 + wave * 32;

    // Gather A fragments for layer 1: mask = [x_i | x_j | ea], K = 160 (5 kt)
    short8 a1[2][5];
#pragma unroll
    for (int mt = 0; mt < 2; ++mt) {
      int e = ebase + mt * 16 + m;
      e = (e < E) ? e : (E - 1);
      const int i0 = ei[e];
      const int i1 = ei[E + e];
      if constexpr (XB) {
        const short* r0 = xb + (size_t)i0 * 64 + quad * 8;
        const short* r1 = xb + (size_t)i1 * 64 + quad * 8;
        a1[mt][0] = *(const short8*)r0;
        a1[mt][1] = *(const short8*)(r0 + 32);
        a1[mt][2] = *(const short8*)r1;
        a1[mt][3] = *(const short8*)(r1 + 32);
      } else {
        const float* r0 = x + (size_t)i0 * 64 + quad * 8;
        const float* r1 = x + (size_t)i1 * 64 + quad * 8;
        a1[mt][0] = cvt8(r0);
        a1[mt][1] = cvt8(r0 + 32);
        a1[mt][2] = cvt8(r1);
        a1[mt][3] = cvt8(r1 + 32);
      }
      a1[mt][4] = cvt8(ea + (size_t)e * 32 + quad * 8);
    }

    f32x4 acc2[2][4];
#pragma unroll
    for (int mt = 0; mt < 2; ++mt)
#pragma unroll
      for (int ot = 0; ot < 4; ++ot) {
        f32x4 z = { b2v[ot], b2v[ot], b2v[ot], b2v[ot] };
        acc2[mt][ot] = z;
      }

    // Stream h in 32-col chunks: produce 2 n-tiles, round-trip LDS, consume in layer 2
#pragma unroll
    for (int c = 0; c < 4; ++c) {
#pragma unroll
      for (int sub = 0; sub < 2; ++sub) {
        const int nt = c * 2 + sub;
        f32x4 h0 = { b1v[nt], b1v[nt], b1v[nt], b1v[nt] };
        f32x4 h1 = h0;
#pragma unroll
        for (int kt = 0; kt < 5; ++kt) {
          short8 bf = *(const short8*)&sW1[(nt * 16 + m) * 168 + kt * 32 + quad * 8];
          h0 = __builtin_amdgcn_mfma_f32_16x16x32_bf16(a1[0][kt], bf, h0, 0, 0, 0);
          h1 = __builtin_amdgcn_mfma_f32_16x16x32_bf16(a1[1][kt], bf, h1, 0, 0, 0);
        }
#pragma unroll
        for (int r = 0; r < 4; ++r) {
          float v0 = h0[r]; v0 = (v0 >= 0.0f) ? v0 : 0.01f * v0;
          float v1 = h1[r]; v1 = (v1 >= 0.0f) ? v1 : 0.01f * v1;
          sHw[(quad * 4 + r) * 40 + sub * 16 + m]      = f2bf(v0);  // m-tile 0: rows 0..15
          sHw[(16 + quad * 4 + r) * 40 + sub * 16 + m] = f2bf(v1);  // m-tile 1: rows 16..31
        }
      }
#pragma unroll
      for (int mt = 0; mt < 2; ++mt) {
        short8 a2 = *(const short8*)&sHw[(mt * 16 + m) * 40 + quad * 8];
#pragma unroll
        for (int ot = 0; ot < 4; ++ot) {
          short8 w2 = sW2f[(ot * 4 + c) * 64 + lane];
          acc2[mt][ot] = __builtin_amdgcn_mfma_f32_16x16x32_bf16(a2, w2, acc2[mt][ot], 0, 0, 0);
        }
      }
    }

    // Store: out[e][o], e = ebase + mt*16 + quad*4 + r, o = ot*16 + m
    // (byte-identical pattern to round 0's proven-clean stores)
#pragma unroll
    for (int mt = 0; mt < 2; ++mt)
#pragma unroll
      for (int ot = 0; ot < 4; ++ot)
#pragma unroll
        for (int r = 0; r < 4; ++r) {
          int er = ebase + mt * 16 + quad * 4 + r;
          if (er < E) out[(size_t)er * 64 + ot * 16 + m] = acc2[mt][ot][r];
        }
  }
}

extern "C" void kernel_launch(void* const* d_in, const int* in_sizes, int n_in,
                              void* d_out, int out_size, void* d_ws, size_t ws_size,
                              hipStream_t stream) {
  const float* x  = (const float*)d_in[0];
  const int*   ei = (const int*)d_in[1];
  const float* ea = (const float*)d_in[2];
  const float* W1 = (const float*)d_in[3];
  const float* b1 = (const float*)d_in[4];
  const float* W2 = (const float*)d_in[5];
  const float* b2 = (const float*)d_in[6];
  float* out = (float*)d_out;

  const int E  = in_sizes[1] / 2;          // edge_index is [2, E]
  const int nx = in_sizes[0];              // N_NODES * DIM_NODE floats
  const int ntiles = (E + 255) / 256;      // 256 edges per block (32 per wave)
  int grid = ntiles < 512 ? ntiles : 512;  // 2 blocks/CU x 256 CU, persistent

  short* xb = (short*)d_ws;
  const bool usebf = (d_ws != nullptr) && (ws_size >= (size_t)nx * sizeof(short))
                     && ((nx & 7) == 0);
  if (usebf) {
    const int n8 = nx / 8;
    const int cg = (n8 + 255) / 256;
    cvt_x_kernel<<<cg, 256, 0, stream>>>(x, xb, n8);
    edge_mlp<true><<<grid, 512, 0, stream>>>(x, xb, ei, ea, W1, b1, W2, b2, out, E, ntiles);
  } else {
    edge_mlp<false><<<grid, 512, 0, stream>>>(x, nullptr, ei, ea, W1, b1, W2, b2, out, E, ntiles);
  }
}